// Round 1
// baseline (1409.605 us; speedup 1.0000x reference)
//
#include <hip/hip_runtime.h>

#define HDIM 64
#define NSTEPS 4

// Packed weight layout in d_ws (float offsets):
//   [0,    256): L1 pack: per k, float4 (W1[k][0], W1[k][1], W1[k][2], b1[k])
//   [256, 4352): W2T[k][j] = W2[j][k+1]                  (64x64)
//   [4352,8448): QT[k][j]  = P[k][j] * W2[j][k+1]        (64x64)
//                where P[k][j] = W1[k][1]*W3[0][j+1] + W1[k][2]*W3[1][j+1]
//   [8448,8576): C2 per j: float2 (W2[j][0], b2[j])
//   [8576,8704): L3 per j: float2 (W3[0][j+1], W3[1][j+1])
//   [8704,8708): C3: (W3[0][0], W3[1][0], b3[0], b3[1])

__global__ void ffjord_prep(const float* __restrict__ W1, const float* __restrict__ b1,
                            const float* __restrict__ W2, const float* __restrict__ b2,
                            const float* __restrict__ W3, const float* __restrict__ b3,
                            float* __restrict__ ws) {
  int tid = threadIdx.x;  // single block, 256 threads
  if (tid < HDIM) {
    ws[tid * 4 + 0] = W1[tid * 3 + 0];
    ws[tid * 4 + 1] = W1[tid * 3 + 1];
    ws[tid * 4 + 2] = W1[tid * 3 + 2];
    ws[tid * 4 + 3] = b1[tid];
    ws[8448 + tid * 2 + 0] = W2[tid * 65 + 0];
    ws[8448 + tid * 2 + 1] = b2[tid];
    ws[8576 + tid * 2 + 0] = W3[0 * 65 + tid + 1];
    ws[8576 + tid * 2 + 1] = W3[1 * 65 + tid + 1];
  }
  if (tid == 0) {
    ws[8704] = W3[0];
    ws[8705] = W3[65];
    ws[8706] = b3[0];
    ws[8707] = b3[1];
  }
  for (int e = tid; e < HDIM * HDIM; e += 256) {
    int k = e >> 6, j = e & 63;
    float w2 = W2[j * 65 + k + 1];
    float p = W1[k * 3 + 1] * W3[j + 1] + W1[k * 3 + 2] * W3[65 + j + 1];
    ws[256 + e] = w2;       // W2T[k][j]
    ws[4352 + e] = p * w2;  // QT[k][j]
  }
}

__global__ __launch_bounds__(256, 2) void ffjord_main(
    const float* __restrict__ z_in, const float* __restrict__ dlp_in,
    const float* __restrict__ ws, float* __restrict__ out, int B) {
  int i = blockIdx.x * 256 + threadIdx.x;
  if (i >= B) return;

  const float4* L1  = (const float4*)(ws);
  const float*  W2T = ws + 256;
  const float*  QT  = ws + 4352;
  const float2* C2  = (const float2*)(ws + 8448);
  const float2* L3  = (const float2*)(ws + 8576);
  const float c30 = ws[8704], c31 = ws[8705], cb0 = ws[8706], cb1 = ws[8707];

  float z0 = z_in[2 * i], z1 = z_in[2 * i + 1];
  float l = dlp_in[i];
  const float dt = 1.0f / NSTEPS;

  #pragma unroll 1
  for (int step = 0; step < NSTEPS; ++step) {
    float t0 = step * dt;
    float az0 = 0.f, az1 = 0.f, al = 0.f;
    float zt0 = z0, zt1 = z1, ts = t0;

    #pragma unroll 1
    for (int s = 0; s < 4; ++s) {
      // ---- dynamics eval at (ts, zt): z_dot and exact divergence ----
      float h2[HDIM], q[HDIM];
      #pragma unroll
      for (int j = 0; j < HDIM; ++j) {
        float2 c2 = C2[j];
        h2[j] = fmaf(c2.x, ts, c2.y);  // W2[:,0]*t + b2
        q[j] = 0.f;
      }

      #pragma unroll 1
      for (int k = 0; k < HDIM; ++k) {
        float4 w1 = L1[k];
        float a = fmaf(w1.x, ts, fmaf(w1.y, zt0, fmaf(w1.z, zt1, w1.w)));
        float aa = fabsf(a);
        float e = __expf(-aa);
        float r = __builtin_amdgcn_rcpf(1.0f + e);
        float sg = (a >= 0.f ? 1.0f : e) * r;              // sigmoid(a)
        float sp = fmaxf(a, 0.f) + __logf(1.0f + e);       // softplus(a)
        const float* w2row = W2T + k * 64;
        const float* qrow  = QT + k * 64;
        #pragma unroll
        for (int j = 0; j < HDIM; ++j) {
          h2[j] = fmaf(w2row[j], sp, h2[j]);
          q[j]  = fmaf(qrow[j], sg, q[j]);
        }
      }

      float zd0 = fmaf(c30, ts, cb0);
      float zd1 = fmaf(c31, ts, cb1);
      float dv = 0.f;
      #pragma unroll
      for (int j = 0; j < HDIM; ++j) {
        float a = h2[j];
        float aa = fabsf(a);
        float e = __expf(-aa);
        float r = __builtin_amdgcn_rcpf(1.0f + e);
        float sg = (a >= 0.f ? 1.0f : e) * r;
        float sp = fmaxf(a, 0.f) + __logf(1.0f + e);
        float2 l3 = L3[j];
        zd0 = fmaf(l3.x, sp, zd0);
        zd1 = fmaf(l3.y, sp, zd1);
        dv = fmaf(sg, q[j], dv);
      }

      // ---- RK4 combine ----
      float w = (s == 1 || s == 2) ? 2.0f : 1.0f;
      az0 = fmaf(w, zd0, az0);
      az1 = fmaf(w, zd1, az1);
      al = fmaf(w, dv, al);
      if (s < 3) {
        float c = (s == 2) ? dt : 0.5f * dt;
        zt0 = fmaf(c, zd0, z0);
        zt1 = fmaf(c, zd1, z1);
        ts = t0 + c;
      }
    }
    z0 = fmaf(dt / 6.0f, az0, z0);
    z1 = fmaf(dt / 6.0f, az1, z1);
    l = fmaf(-dt / 6.0f, al, l);  // k_l = -div
  }

  out[2 * i] = z0;
  out[2 * i + 1] = z1;
  out[2 * B + i] = l;
}

extern "C" void kernel_launch(void* const* d_in, const int* in_sizes, int n_in,
                              void* d_out, int out_size, void* d_ws, size_t ws_size,
                              hipStream_t stream) {
  const float* z   = (const float*)d_in[0];
  const float* dlp = (const float*)d_in[1];
  const float* W1  = (const float*)d_in[2];
  const float* b1  = (const float*)d_in[3];
  const float* W2  = (const float*)d_in[4];
  const float* b2  = (const float*)d_in[5];
  const float* W3  = (const float*)d_in[6];
  const float* b3  = (const float*)d_in[7];
  float* out = (float*)d_out;
  float* ws = (float*)d_ws;

  int B = in_sizes[0] / 2;

  ffjord_prep<<<1, 256, 0, stream>>>(W1, b1, W2, b2, W3, b3, ws);
  int blocks = (B + 255) / 256;
  ffjord_main<<<blocks, 256, 0, stream>>>(z, dlp, ws, out, B);
}